// Round 6
// baseline (6238.720 us; speedup 1.0000x reference)
//
#include <hip/hip_runtime.h>

#define T_LEN 3000
#define BATCH 64
#define G4 100   // 4*H, H=25

// ---------------------------------------------------------------------------
// GEMM v2: xg[dir][row][j] = bias[j] + sum_k x(row,k) * w_ih[dir][j][k]
// 256-row tile per block (R=4 rows per lane, row-interleaved lane+64j),
// 100 cols (4 waves x 25). Per k4: 16 LDS b32 (x) + 25 b128 broadcast (w)
// per 400 fma. MODE 0: x layout (B,T,F); MODE 1: (T,B,K).
// K-tail: x loads address-clamped (garbage ok), w zero-guarded.
// ---------------------------------------------------------------------------
template <int MODE>
__global__ __launch_bounds__(256, 2) void gemm_xg(
    const float* __restrict__ in, const float* __restrict__ w_ih,
    const float* __restrict__ b_ih, const float* __restrict__ b_hh,
    float* __restrict__ xg, int K) {
  __shared__ float lds_x[256][33];                // stride 33: (lane+kk)%32 banks, 2-way free
  __shared__ __align__(16) float lds_w[100][32];  // rows 128B-aligned for b128 broadcast

  const int tid = threadIdx.x;
  const int dir = blockIdx.y;
  const int r0 = blockIdx.x * 256;
  const int lane = tid & 63;
  const int wv = tid >> 6;
  const int c0 = wv * 25;
  const float* wbase = w_ih + (size_t)dir * G4 * K;

  float acc[4][25];
#pragma unroll
  for (int c = 0; c < 25; ++c) {
    float bias = b_ih[dir * G4 + c0 + c] + b_hh[dir * G4 + c0 + c];
#pragma unroll
    for (int j = 0; j < 4; ++j) acc[j][c] = bias;
  }

  for (int k0 = 0; k0 < K; k0 += 32) {
    const int kw = min(32, K - k0);
    // stage x: 256 rows x 32 k as float2 (rows are 8B-aligned: K even)
#pragma unroll
    for (int it = 0; it < 16; ++it) {
      int idx = it * 256 + tid;        // 0..4095
      int row = idx >> 4;              // 0..255 (16 threads per row -> coalesced)
      int kp = (idx & 15) * 2;         // 0,2,..,30
      int grow = r0 + row;
      const float* rp;
      if (MODE == 0) {
        int tt = grow >> 6, bb = grow & 63;   // row = t*64 + b
        rp = in + ((size_t)bb * T_LEN + tt) * K;
      } else {
        rp = in + (size_t)grow * K;
      }
      int kc = min(k0 + kp, K - 2);    // clamp: garbage values hit w=0
      float2 v = *(const float2*)(rp + kc);
      lds_x[row][kp] = v.x;
      lds_x[row][kp + 1] = v.y;
    }
    // stage w: 100 rows x 32 k, zero-guarded scalar
#pragma unroll
    for (int i = 0; i < 13; ++i) {
      int e = tid + i * 256;
      if (e < 3200) {
        int j = e >> 5, kk = e & 31;
        lds_w[j][kk] = (kk < kw) ? wbase[(size_t)j * K + k0 + kk] : 0.f;
      }
    }
    __syncthreads();
#pragma unroll
    for (int k4 = 0; k4 < 8; ++k4) {
      float xv[4][4];
#pragma unroll
      for (int j = 0; j < 4; ++j)
#pragma unroll
        for (int e = 0; e < 4; ++e)
          xv[j][e] = lds_x[lane + 64 * j][k4 * 4 + e];
#pragma unroll
      for (int c = 0; c < 25; ++c) {
        float4 w4 = *(const float4*)&lds_w[c0 + c][k4 * 4];  // wave-uniform broadcast
#pragma unroll
        for (int j = 0; j < 4; ++j) {
          acc[j][c] = fmaf(xv[j][0], w4.x, acc[j][c]);
          acc[j][c] = fmaf(xv[j][1], w4.y, acc[j][c]);
          acc[j][c] = fmaf(xv[j][2], w4.z, acc[j][c]);
          acc[j][c] = fmaf(xv[j][3], w4.w, acc[j][c]);
        }
      }
    }
    __syncthreads();
  }
#pragma unroll
  for (int j = 0; j < 4; ++j) {
    const int row = r0 + lane + 64 * j;
    float* orow = xg + ((size_t)dir * T_LEN * BATCH + row) * G4 + c0;
#pragma unroll
    for (int c = 0; c < 25; ++c) orow[c] = acc[j][c];
  }
}

// ---------------------------------------------------------------------------
// Fast activations (v_rcp_f32, 1 ulp — absmax margin is 6x).
// ---------------------------------------------------------------------------
__device__ __forceinline__ float frcp(float x) { return __builtin_amdgcn_rcpf(x); }
__device__ __forceinline__ float sigm(float x) { return frcp(1.f + __expf(-x)); }
__device__ __forceinline__ float tanh_f(float x) { return 1.f - 2.f * frcp(__expf(2.f * x) + 1.f); }

// ---------------------------------------------------------------------------
// LSTM scan v6: one wave = TWO same-direction sequences (b0, b0+1), shared
// weights. 64 blocks x 64 threads. Lane n<25: gates (i,g); lane 32+n:
// (f,o) + cell. Zero lgkm ops in the recurrence: u via permlane32_swap
// (VALU), h via 25x readlane (VALU->SGPR) -> no shared-counter coupling,
// the two sequences' chains interleave in each other's stall gaps.
// xg prefetch: 2 chunks x 4 steps in flight per seq.
// ---------------------------------------------------------------------------
typedef int v2i __attribute__((ext_vector_type(2)));

__global__ __launch_bounds__(64)
__attribute__((amdgpu_waves_per_eu(1, 1)))
void lstm_scan(
    const float* __restrict__ xg,    // [2][T][B][100]
    const float* __restrict__ w_hh,  // [2][100][25]
    float* __restrict__ hout) {      // [T][B][50]
  const int dir = blockIdx.x & 1;
  const int b0 = (blockIdx.x >> 1) * 2;
  const int lane = threadIdx.x;
  const bool isC = lane >= 32;
  const int nn = lane & 31;
  const int n = (nn < 25) ? nn : 24;         // clamp idle lanes
  const bool writer = isC && (nn < 25);
  const int qA = n + (isC ? 25 : 0);         // gate row: i_n or f_n
  const int qB = qA + 50;                    // gate row: g_n or o_n

  // one-time permlane32_swap semantics probe (loop-invariant -> 1 cndmask/step)
  v2i tr = __builtin_amdgcn_permlane32_swap(lane, lane, 0, 0);
  const bool pick0 = (tr[0] == (lane ^ 32));

  // shared per-lane weights, pinned register-resident (volatile: no remat)
  const float* wb = w_hh + (size_t)dir * G4 * 25;
  float wA[25], wB[25];
#pragma unroll
  for (int k = 0; k < 25; ++k) {
    wA[k] = wb[qA * 25 + k];
    wB[k] = wb[qB * 25 + k];
  }
#pragma unroll
  for (int k = 0; k < 25; ++k) {
    asm volatile("" : "+v"(wA[k]), "+v"(wB[k]));
  }

  float hs0[25], hs1[25], c0 = 0.f, c1 = 0.f;
#pragma unroll
  for (int k = 0; k < 25; ++k) { hs0[k] = 0.f; hs1[k] = 0.f; }

  const float* xb0 = xg + (size_t)dir * T_LEN * BATCH * G4 + (size_t)b0 * G4;
  const float* xb1 = xb0 + G4;

  auto xrow = [&](const float* xb, int s) -> const float* {
    int ss = min(s, T_LEN - 1);
    int t = dir ? (T_LEN - 1 - ss) : ss;
    return xb + (size_t)t * (BATCH * G4);
  };

  auto loadchunk = [&](float (&dst)[4][2], const float* xb, int s0) {
#pragma unroll
    for (int d = 0; d < 4; ++d) {
      const float* r = xrow(xb, s0 + d);
      dst[d][0] = r[qA];
      dst[d][1] = r[qB];
    }
  };

  auto step = [&](float (&p)[2], float (&hs)[25], float& cc, int bglob, int s) {
    float pA = p[0], pB = p[1];
#pragma unroll
    for (int k = 0; k < 25; ++k) {
      pA = fmaf(wA[k], hs[k], pA);
      pB = fmaf(wB[k], hs[k], pB);
    }
    float aA = sigm(pA);                       // sigm(i) | sigm(f)
    float xbv = isC ? pB : (pB + pB);
    float sb = sigm(xbv);
    float bg = isC ? sb : fmaf(2.f, sb, -1.f); // sigm(o) | tanh(g)
    float u = aA * bg;                         // i*g on A-lanes
    int ui = __float_as_int(u);
    v2i r = __builtin_amdgcn_permlane32_swap(ui, ui, 0, 0);
    float uu = __int_as_float(pick0 ? r[0] : r[1]);  // u_n lands on lane 32+n
    cc = fmaf(aA, cc, uu);                     // f*c + i*g (C-lanes)
    float hn = bg * tanh_f(cc);                // o*tanh(c) (C-lanes)
    if (writer) {
      int t = dir ? (T_LEN - 1 - s) : s;
      hout[((size_t)t * BATCH + bglob) * 50 + dir * 25 + n] = hn;
    }
    int hi = __float_as_int(hn);
#pragma unroll
    for (int k = 0; k < 25; ++k)
      hs[k] = __int_as_float(__builtin_amdgcn_readlane(hi, 32 + k));
  };

  float pf0[2][4][2], pf1[2][4][2];
  loadchunk(pf0[0], xb0, 0);
  loadchunk(pf1[0], xb1, 0);
  loadchunk(pf0[1], xb0, 4);
  loadchunk(pf1[1], xb1, 4);

  for (int s0 = 0; s0 < T_LEN; s0 += 8) {   // 375 iterations
#pragma unroll
    for (int ph = 0; ph < 2; ++ph) {
#pragma unroll
      for (int d = 0; d < 4; ++d) {
        step(pf0[ph][d], hs0, c0, b0, s0 + ph * 4 + d);
        step(pf1[ph][d], hs1, c1, b0 + 1, s0 + ph * 4 + d);
      }
      loadchunk(pf0[ph], xb0, s0 + 8 + ph * 4);   // refill right after last use
      loadchunk(pf1[ph], xb1, s0 + 8 + ph * 4);
    }
  }
}

// ---------------------------------------------------------------------------
// FC: out[b][t][m] = sum_j h[t][b][j] * fc_w[m][j] + fc_b[m]
// ---------------------------------------------------------------------------
__global__ __launch_bounds__(256) void fc_kernel(
    const float* __restrict__ h, const float* __restrict__ fc_w,
    const float* __restrict__ fc_b, float* __restrict__ out) {
  int row = blockIdx.x * 256 + threadIdx.x;  // row = t*B + b
  if (row >= T_LEN * BATCH) return;
  int t = row >> 6, b = row & 63;
  const float* hr = h + (size_t)row * 50;
  float a0 = fc_b[0], a1 = fc_b[1], a2 = fc_b[2];
#pragma unroll
  for (int j = 0; j < 50; ++j) {
    float v = hr[j];
    a0 = fmaf(v, fc_w[j], a0);
    a1 = fmaf(v, fc_w[50 + j], a1);
    a2 = fmaf(v, fc_w[100 + j], a2);
  }
  float* op = out + ((size_t)b * T_LEN + t) * 3;
  op[0] = a0; op[1] = a1; op[2] = a2;
}

// ---------------------------------------------------------------------------
extern "C" void kernel_launch(void* const* d_in, const int* in_sizes, int n_in,
                              void* d_out, int out_size, void* d_ws, size_t ws_size,
                              hipStream_t stream) {
  const float* x = (const float*)d_in[0];
  const float* w_ih[3] = {(const float*)d_in[1], (const float*)d_in[5], (const float*)d_in[9]};
  const float* w_hh[3] = {(const float*)d_in[2], (const float*)d_in[6], (const float*)d_in[10]};
  const float* b_ih[3] = {(const float*)d_in[3], (const float*)d_in[7], (const float*)d_in[11]};
  const float* b_hh[3] = {(const float*)d_in[4], (const float*)d_in[8], (const float*)d_in[12]};
  const float* fc_w = (const float*)d_in[13];
  const float* fc_b = (const float*)d_in[14];
  float* out = (float*)d_out;

  float* xg = (float*)d_ws;                                 // 2*T*B*100 fp32 = 153.6 MB
  float* hA = xg + (size_t)2 * T_LEN * BATCH * G4;          // T*B*50 = 38.4 MB
  float* hB = hA + (size_t)T_LEN * BATCH * 50;              // T*B*50 = 38.4 MB

  dim3 gg(T_LEN * BATCH / 256, 2), gb(256);

  // layer 0
  hipLaunchKernelGGL((gemm_xg<0>), gg, gb, 0, stream, x, w_ih[0], b_ih[0], b_hh[0], xg, 314);
  hipLaunchKernelGGL(lstm_scan, dim3(BATCH), dim3(64), 0, stream, xg, w_hh[0], hA);
  // layer 1
  hipLaunchKernelGGL((gemm_xg<1>), gg, gb, 0, stream, hA, w_ih[1], b_ih[1], b_hh[1], xg, 50);
  hipLaunchKernelGGL(lstm_scan, dim3(BATCH), dim3(64), 0, stream, xg, w_hh[1], hB);
  // layer 2
  hipLaunchKernelGGL((gemm_xg<1>), gg, gb, 0, stream, hB, w_ih[2], b_ih[2], b_hh[2], xg, 50);
  hipLaunchKernelGGL(lstm_scan, dim3(BATCH), dim3(64), 0, stream, xg, w_hh[2], hA);
  // fc
  hipLaunchKernelGGL(fc_kernel, dim3(T_LEN * BATCH / 256), dim3(256), 0, stream, hA, fc_w, fc_b, out);
}

// Round 7
// 4769.219 us; speedup vs baseline: 1.3081x; 1.3081x over previous
//
#include <hip/hip_runtime.h>

#define T_LEN 3000
#define BATCH 64
#define G4 100   // 4*H, H=25

#define LOG2E 1.442695041f
// xg pre-scale per gate block (exp2-domain activations in the scan):
// i,f,o: -log2e ; g: +2*log2e

// ---------------------------------------------------------------------------
// GEMM v2b: xg[dir][row][j] = SCALE_j * (bias[j] + sum_k x(row,k)*w_ih[dir][j][k])
// 256-row tile (R=4 rows/lane), 100 cols (4 waves x 25). Plain launch_bounds
// (r6's ",2" capped VGPR at 128 and spilled acc[100]).
// ---------------------------------------------------------------------------
template <int MODE>
__global__ __launch_bounds__(256) void gemm_xg(
    const float* __restrict__ in, const float* __restrict__ w_ih,
    const float* __restrict__ b_ih, const float* __restrict__ b_hh,
    float* __restrict__ xg, int K) {
  __shared__ float lds_x[256][33];                // stride 33: 2-way bank alias (free)
  __shared__ __align__(16) float lds_w[100][32];  // rows 128B-aligned for b128 broadcast

  const int tid = threadIdx.x;
  const int dir = blockIdx.y;
  const int r0 = blockIdx.x * 256;
  const int lane = tid & 63;
  const int wv = tid >> 6;
  const int c0 = wv * 25;
  const float* wbase = w_ih + (size_t)dir * G4 * K;

  float acc[4][25];
#pragma unroll
  for (int c = 0; c < 25; ++c) {
    float bias = b_ih[dir * G4 + c0 + c] + b_hh[dir * G4 + c0 + c];
#pragma unroll
    for (int j = 0; j < 4; ++j) acc[j][c] = bias;
  }

  for (int k0 = 0; k0 < K; k0 += 32) {
    const int kw = min(32, K - k0);
    // stage x: 256 rows x 32 k as float2 (16 threads/row -> coalesced 128B)
#pragma unroll
    for (int it = 0; it < 16; ++it) {
      int idx = it * 256 + tid;        // 0..4095
      int row = idx >> 4;
      int kp = (idx & 15) * 2;
      int grow = r0 + row;
      const float* rp;
      if (MODE == 0) {
        int tt = grow >> 6, bb = grow & 63;   // row = t*64 + b
        rp = in + ((size_t)bb * T_LEN + tt) * K;
      } else {
        rp = in + (size_t)grow * K;
      }
      int kc = min(k0 + kp, K - 2);    // clamp: garbage hits w=0
      float2 v = *(const float2*)(rp + kc);
      lds_x[row][kp] = v.x;
      lds_x[row][kp + 1] = v.y;
    }
    // stage w: 100 rows x 32 k, zero-guarded
#pragma unroll
    for (int i = 0; i < 13; ++i) {
      int e = tid + i * 256;
      if (e < 3200) {
        int j = e >> 5, kk = e & 31;
        lds_w[j][kk] = (kk < kw) ? wbase[(size_t)j * K + k0 + kk] : 0.f;
      }
    }
    __syncthreads();
#pragma unroll
    for (int k4 = 0; k4 < 8; ++k4) {
      float xv[4][4];
#pragma unroll
      for (int j = 0; j < 4; ++j)
#pragma unroll
        for (int e = 0; e < 4; ++e)
          xv[j][e] = lds_x[lane + 64 * j][k4 * 4 + e];
#pragma unroll
      for (int c = 0; c < 25; ++c) {
        float4 w4 = *(const float4*)&lds_w[c0 + c][k4 * 4];  // wave-uniform broadcast
#pragma unroll
        for (int j = 0; j < 4; ++j) {
          acc[j][c] = fmaf(xv[j][0], w4.x, acc[j][c]);
          acc[j][c] = fmaf(xv[j][1], w4.y, acc[j][c]);
          acc[j][c] = fmaf(xv[j][2], w4.z, acc[j][c]);
          acc[j][c] = fmaf(xv[j][3], w4.w, acc[j][c]);
        }
      }
    }
    __syncthreads();
  }
  // epilogue: exp2-domain pre-scale (wave-uniform): cols 50-74 = g gate
  const float sc = (wv == 2) ? 2.f * LOG2E : -LOG2E;
#pragma unroll
  for (int j = 0; j < 4; ++j) {
    const int row = r0 + lane + 64 * j;
    float* orow = xg + ((size_t)dir * T_LEN * BATCH + row) * G4 + c0;
#pragma unroll
    for (int c = 0; c < 25; ++c) orow[c] = acc[j][c] * sc;
  }
}

// ---------------------------------------------------------------------------
__device__ __forceinline__ float frcp(float x) { return __builtin_amdgcn_rcpf(x); }
__device__ __forceinline__ float exp2f_fast(float x) {
  float r;
  asm("v_exp_f32 %0, %1" : "=v"(r) : "v"(x));
  return r;
}

// ---------------------------------------------------------------------------
// LSTM scan v7: one sequence per wave, 512-thread blocks (8 waves = 2 waves
// per SIMD guaranteed) -> HARDWARE interleaves two waves' dep chains on each
// SIMD (in-order waves can't get ILP from the compiler; get TLP instead).
// Lane n<25: gates (i,g). Lane 32+n: (f,o) + cell. u via permlane32_swap,
// h via 25x readlane->SGPR. Gates in exp2 domain (inputs pre-scaled).
// hn buffered 8 steps in static regs, stores flushed per 8 (no per-step
// branch in the step body). grid = 16 blocks x 512.
// ---------------------------------------------------------------------------
typedef int v2i __attribute__((ext_vector_type(2)));

__global__ __launch_bounds__(512) void lstm_scan(
    const float* __restrict__ xg,    // [2][T][B][100] (pre-scaled)
    const float* __restrict__ w_hh,  // [2][100][25]
    float* __restrict__ hout) {      // [T][B][50]
  const int wid = threadIdx.x >> 6;
  const int lane = threadIdx.x & 63;
  const int seq = blockIdx.x * 8 + wid;      // 0..127
  const int dir = seq & 1;
  const int b = seq >> 1;
  const bool isC = lane >= 32;
  const int nn = lane & 31;
  const int n = (nn < 25) ? nn : 24;         // clamp idle lanes
  const bool writer = isC && (nn < 25);
  const int qA = n + (isC ? 25 : 0);         // gate row: i_n | f_n
  const int qB = qA + 50;                    // gate row: g_n | o_n

  // one-time permlane32_swap semantics probe
  v2i tr = __builtin_amdgcn_permlane32_swap(lane, lane, 0, 0);
  const bool pick0 = (tr[0] == (lane ^ 32));

  // weights, pre-scaled into exp2 domain, pinned register-resident
  const float sA = -LOG2E;                       // i | f  (sigm)
  const float sB = isC ? -LOG2E : 2.f * LOG2E;   // o (sigm) | g (tanh)
  const float* wb = w_hh + (size_t)dir * G4 * 25;
  float wA[25], wB[25];
#pragma unroll
  for (int k = 0; k < 25; ++k) {
    wA[k] = wb[qA * 25 + k] * sA;
    wB[k] = wb[qB * 25 + k] * sB;
  }
#pragma unroll
  for (int k = 0; k < 25; ++k) {
    asm volatile("" : "+v"(wA[k]), "+v"(wB[k]));
  }

  float hs[25];
#pragma unroll
  for (int k = 0; k < 25; ++k) hs[k] = 0.f;
  float c = 0.f;

  const float* xb = xg + (size_t)dir * T_LEN * BATCH * G4 + (size_t)b * G4;

  auto loadchunk = [&](float (&dst)[4][2], int s0) {
#pragma unroll
    for (int d = 0; d < 4; ++d) {
      int ss = min(s0 + d, T_LEN - 1);
      int t = dir ? (T_LEN - 1 - ss) : ss;
      const float* r = xb + (size_t)t * (BATCH * G4);
      dst[d][0] = r[qA];
      dst[d][1] = r[qB];
    }
  };

  auto step = [&](float (&p)[2]) -> float {
    float pA = p[0], pB = p[1];
#pragma unroll
    for (int k = 0; k < 25; ++k) {
      pA = fmaf(wA[k], hs[k], pA);
      pB = fmaf(wB[k], hs[k], pB);
    }
    // exp2-domain activations: sigm(x)=rcp(1+2^(-x*log2e)), tanh(x)=1-2*rcp(2^(2x*log2e)+1)
    float aA = frcp(1.f + exp2f_fast(pA));          // sigm(i) | sigm(f)
    float rB = frcp(1.f + exp2f_fast(pB));
    float bg = isC ? rB : fmaf(-2.f, rB, 1.f);      // sigm(o) | tanh(g)
    float u = aA * bg;                              // i*g on A-lanes
    int ui = __float_as_int(u);
    v2i r = __builtin_amdgcn_permlane32_swap(ui, ui, 0, 0);
    float uu = __int_as_float(pick0 ? r[0] : r[1]); // u_n -> lane 32+n
    c = fmaf(aA, c, uu);                            // f*c + i*g (C-lanes)
    float tc = fmaf(-2.f, frcp(1.f + exp2f_fast(2.f * LOG2E * c)), 1.f);
    float hn = bg * tc;                             // o*tanh(c) (C-lanes)
    int hi = __float_as_int(hn);
#pragma unroll
    for (int k = 0; k < 25; ++k)
      hs[k] = __int_as_float(__builtin_amdgcn_readlane(hi, 32 + k));
    return hn;
  };

  float pf[2][4][2];
  loadchunk(pf[0], 0);
  loadchunk(pf[1], 4);

  const ptrdiff_t hstr = dir ? -(BATCH * 50) : (BATCH * 50);

  for (int s0 = 0; s0 < T_LEN; s0 += 8) {   // 375 iterations
    float hb[8];
#pragma unroll
    for (int d = 0; d < 4; ++d) hb[d] = step(pf[0][d]);
    loadchunk(pf[0], s0 + 8);
#pragma unroll
    for (int d = 0; d < 4; ++d) hb[4 + d] = step(pf[1][d]);
    loadchunk(pf[1], s0 + 12);
    // burst-flush 8 steps of output
    if (writer) {
      int t0 = dir ? (T_LEN - 1 - s0) : s0;
      float* p = hout + ((size_t)t0 * BATCH + b) * 50 + dir * 25 + n;
#pragma unroll
      for (int d = 0; d < 8; ++d) p[(ptrdiff_t)d * hstr] = hb[d];
    }
  }
}

// ---------------------------------------------------------------------------
// FC: out[b][t][m] = sum_j h[t][b][j] * fc_w[m][j] + fc_b[m]
// ---------------------------------------------------------------------------
__global__ __launch_bounds__(256) void fc_kernel(
    const float* __restrict__ h, const float* __restrict__ fc_w,
    const float* __restrict__ fc_b, float* __restrict__ out) {
  int row = blockIdx.x * 256 + threadIdx.x;  // row = t*B + b
  if (row >= T_LEN * BATCH) return;
  int t = row >> 6, b = row & 63;
  const float* hr = h + (size_t)row * 50;
  float a0 = fc_b[0], a1 = fc_b[1], a2 = fc_b[2];
#pragma unroll
  for (int j = 0; j < 50; ++j) {
    float v = hr[j];
    a0 = fmaf(v, fc_w[j], a0);
    a1 = fmaf(v, fc_w[50 + j], a1);
    a2 = fmaf(v, fc_w[100 + j], a2);
  }
  float* op = out + ((size_t)b * T_LEN + t) * 3;
  op[0] = a0; op[1] = a1; op[2] = a2;
}

// ---------------------------------------------------------------------------
extern "C" void kernel_launch(void* const* d_in, const int* in_sizes, int n_in,
                              void* d_out, int out_size, void* d_ws, size_t ws_size,
                              hipStream_t stream) {
  const float* x = (const float*)d_in[0];
  const float* w_ih[3] = {(const float*)d_in[1], (const float*)d_in[5], (const float*)d_in[9]};
  const float* w_hh[3] = {(const float*)d_in[2], (const float*)d_in[6], (const float*)d_in[10]};
  const float* b_ih[3] = {(const float*)d_in[3], (const float*)d_in[7], (const float*)d_in[11]};
  const float* b_hh[3] = {(const float*)d_in[4], (const float*)d_in[8], (const float*)d_in[12]};
  const float* fc_w = (const float*)d_in[13];
  const float* fc_b = (const float*)d_in[14];
  float* out = (float*)d_out;

  float* xg = (float*)d_ws;                                 // 2*T*B*100 fp32 = 153.6 MB
  float* hA = xg + (size_t)2 * T_LEN * BATCH * G4;          // T*B*50 = 38.4 MB
  float* hB = hA + (size_t)T_LEN * BATCH * 50;              // T*B*50 = 38.4 MB

  dim3 gg(T_LEN * BATCH / 256, 2), gb(256);

  // layer 0
  hipLaunchKernelGGL((gemm_xg<0>), gg, gb, 0, stream, x, w_ih[0], b_ih[0], b_hh[0], xg, 314);
  hipLaunchKernelGGL(lstm_scan, dim3(16), dim3(512), 0, stream, xg, w_hh[0], hA);
  // layer 1
  hipLaunchKernelGGL((gemm_xg<1>), gg, gb, 0, stream, hA, w_ih[1], b_ih[1], b_hh[1], xg, 50);
  hipLaunchKernelGGL(lstm_scan, dim3(16), dim3(512), 0, stream, xg, w_hh[1], hB);
  // layer 2
  hipLaunchKernelGGL((gemm_xg<1>), gg, gb, 0, stream, hB, w_ih[2], b_ih[2], b_hh[2], xg, 50);
  hipLaunchKernelGGL(lstm_scan, dim3(16), dim3(512), 0, stream, xg, w_hh[2], hA);
  // fc
  hipLaunchKernelGGL(fc_kernel, dim3(T_LEN * BATCH / 256), dim3(256), 0, stream, hA, fc_w, fc_b, out);
}